// Round 8
// baseline (300.735 us; speedup 1.0000x reference)
//
#include <hip/hip_runtime.h>
#include <cmath>

// ---------------- problem constants ----------------
#define NLAYERS 100      // hidden layers (scan)
#define DIN     64       // input features
#define WDIM    100      // hidden width
#define NTT     4        // 4 n-tiles of 32 (128 neuron cols; bias col = 100)
#define ROWS    32       // rows per WAVE (RT=1)
#define WAVES   4        // waves per block
#define BROWS   (WAVES * ROWS)   // 128 rows per block
#define KS      7        // 7 k-steps of 16 -> K=112 (useful 101)
#define KSL     3        // ks 0..2 delivered via LDS (staged)
#define KST     (KS - KSL)       // ks 3..6 delivered direct global->reg (TCP)
#define FRAGSL  (KSL * NTT)      // 12 staged frags per layer
#define FPW     (FRAGSL / WAVES) // 3 frags staged per wave

typedef _Float16 half8  __attribute__((ext_vector_type(8)));
typedef _Float16 half2v __attribute__((ext_vector_type(2)));
typedef __fp16   fp16x2 __attribute__((ext_vector_type(2)));
typedef float    f32x4  __attribute__((ext_vector_type(4)));
typedef float    f32x16 __attribute__((ext_vector_type(16)));
typedef unsigned uint4v __attribute__((ext_vector_type(4)));

// ---------------- workspace layout ----------------
// wsh: [l][ks7][nt4][lane][8] — frag stride 512 halves (1024 B).
// A-frag (32x32x16, operand-swapped W^T): lane -> neuron n = nt*32+(lane&31);
// elem j -> k = ks*16 + (lane>>5)*8 + j.
//   k<100 && n<100   -> Ws[l][k][n]
//   k==100 && n<100  -> bs[l][n]      (bias row vs h col 100 == 1.0)
//   k==100 && n==100 -> 1.0           (bias col self-sustains)
#define WSH_LAYER_HALVES (KS * NTT * 64 * 8)             // 14336 (28672 B)
#define WSH_HALVES       (NLAYERS * WSH_LAYER_HALVES)    // 1,433,600
#define W0_HALVES        (4 * NTT * 64 * 8)              // 8192 (input, K=64 = 4 ks)
#define BPAD_FLOATS      128                             // b_in padded; col 100 = 1.0
#define OFF_BPAD_B       ((WSH_HALVES + W0_HALVES) * 2)
#define OFF_WOUT_B       (OFF_BPAD_B + BPAD_FLOATS * 4)
#define WOUT_FLOATS      128

// ============================================================
// prep v2 (unchanged): one block per (l,ks); coalesced row reads ->
// 8KB LDS f32 tile [16k][128n] -> coalesced half8 frag stores.
// ============================================================
__global__ __launch_bounds__(256)
void actor_prep(const float* __restrict__ Win, const float* __restrict__ bin,
                const float* __restrict__ Ws,  const float* __restrict__ bs,
                const float* __restrict__ Wout,
                _Float16* __restrict__ wsh, _Float16* __restrict__ w0sh,
                float* __restrict__ bpad, float* __restrict__ woutp) {
    __shared__ float tile[16 * 128];
    const int bid = blockIdx.x, tid = threadIdx.x;
    if (bid < NLAYERS * KS) {                       // hidden-layer weights
        const int l = bid / KS, ks = bid % KS;
#pragma unroll
        for (int e = 0; e < 8; ++e) {
            int idx = tid + 256 * e;                // coalesced: tid fastest
            int kk = idx >> 7, nn = idx & 127;
            int k = ks * 16 + kk;
            float v = 0.f;
            if (k < WDIM && nn < WDIM)        v = Ws[(l * WDIM + k) * WDIM + nn];
            else if (k == WDIM && nn < WDIM)  v = bs[l * WDIM + nn];   // bias row
            else if (k == WDIM && nn == WDIM) v = 1.0f;                // bias col alive
            tile[idx] = v;
        }
        __syncthreads();
        const int lane = tid & 63, nt = tid >> 6;
        const int g = lane >> 5, n = nt * 32 + (lane & 31);
        half8 o;
#pragma unroll
        for (int j = 0; j < 8; ++j) o[j] = (_Float16)tile[(g * 8 + j) * 128 + n];
        *(half8*)(wsh + (((l * KS + ks) * NTT + nt) << 9) + lane * 8) = o;
        return;
    }
    int b2 = bid - NLAYERS * KS;
    if (b2 < 4) {                                   // input layer (K=64)
        const int ks = b2;
#pragma unroll
        for (int e = 0; e < 8; ++e) {
            int idx = tid + 256 * e;
            int kk = idx >> 7, nn = idx & 127;
            int k = ks * 16 + kk;                   // < 64
            tile[idx] = (nn < WDIM) ? Win[k * WDIM + nn] : 0.f;
        }
        __syncthreads();
        const int lane = tid & 63, nt = tid >> 6;
        const int g = lane >> 5, n = nt * 32 + (lane & 31);
        half8 o;
#pragma unroll
        for (int j = 0; j < 8; ++j) o[j] = (_Float16)tile[(g * 8 + j) * 128 + n];
        *(half8*)(w0sh + ((ks * NTT + nt) << 9) + lane * 8) = o;
        return;
    }
    // last block: padded b_in (col 100 = 1.0 seed) + padded W_out
    if (tid < BPAD_FLOATS) {
        bpad[tid] = (tid < WDIM) ? bin[tid] : (tid == WDIM ? 1.0f : 0.f);
    } else {
        int t = tid - BPAD_FLOATS;
        if (t < WOUT_FLOATS) woutp[t] = (t < WDIM) ? Wout[t] : 0.f;
    }
}

// async global->LDS, 16 B per lane, zero VGPR cost.
// g: per-lane source (base + lane*16B); l: WAVE-UNIFORM LDS frag base
// (HW adds lane*16). [m97: emits global_load_lds_dwordx4]
__device__ __forceinline__ void stage16(const _Float16* __restrict__ g,
                                        _Float16* l) {
    __builtin_amdgcn_global_load_lds(
        (const __attribute__((address_space(1))) unsigned*)g,
        (__attribute__((address_space(3))) unsigned*)l, 16, 0, 0);
}

// split fp32 -> hi/lo fp16 (layer-0 input only: keep input fidelity)
__device__ __forceinline__ void split8(const float* __restrict__ p, half8& hi, half8& lo) {
    f32x4 u0 = *(const f32x4*)p;
    f32x4 u1 = *(const f32x4*)(p + 4);
    float v[8] = {u0[0], u0[1], u0[2], u0[3], u1[0], u1[1], u1[2], u1[3]};
#pragma unroll
    for (int e = 0; e < 8; e += 2) {
        fp16x2 h = __builtin_amdgcn_cvt_pkrtz(v[e], v[e + 1]);
        float r0 = v[e]     - (float)h[0];
        float r1 = v[e + 1] - (float)h[1];
        fp16x2 l = __builtin_amdgcn_cvt_pkrtz(r0, r1);
        hi[e] = (_Float16)h[0]; hi[e + 1] = (_Float16)h[1];
        lo[e] = (_Float16)l[0]; lo[e + 1] = (_Float16)l[1];
    }
}

// RNE f16 cast pair + packed-f16 leaky -> one dword (same ops/precision
// as the original LDS epilogue: scalar RNE cast, then max(p, 0.01p) in f16)
__device__ __forceinline__ unsigned pack2(float a, float b) {
    half2v p; p[0] = (_Float16)a; p[1] = (_Float16)b;
    const half2v slope = {(_Float16)0.01f, (_Float16)0.01f};
    p = __builtin_elementwise_max(p, p * slope);
    return __builtin_bit_cast(unsigned, p);
}

// acc -> bh: leaky+f16 pack + lane-half exchange (v_permlane32_swap).
// C/D layout (m74/m101): col=b31, row=(reg&3)+8*(reg>>2)+4g. B-frag:
// lane b31 holds k=ks*16+g*8+j; j0..3 from lane b31 regs r0=8*(ks&1)+0..3,
// j4..7 from lane b31+32 same regs -> one permlane swap per dword pair.
// Bit-identical to the LDS h path (absmax constant 0.09375 since r17).
__device__ __forceinline__ void pack_bh(const f32x16 (&acc)[NTT], half8 (&bh)[KS]) {
#pragma unroll
    for (int ks = 0; ks < KS; ++ks) {
        const int r0 = 8 * (ks & 1);
        const f32x16 a = acc[ks >> 1];
        unsigned lo0 = pack2(a[r0 + 0], a[r0 + 1]);
        unsigned lo1 = pack2(a[r0 + 2], a[r0 + 3]);
        unsigned hi0 = pack2(a[r0 + 4], a[r0 + 5]);
        unsigned hi1 = pack2(a[r0 + 6], a[r0 + 7]);
        asm volatile("v_permlane32_swap_b32 %0, %1" : "+v"(lo0), "+v"(hi0));
        asm volatile("v_permlane32_swap_b32 %0, %1" : "+v"(lo1), "+v"(hi1));
        uint4v u = {lo0, lo1, hi0, hi1};
        bh[ks] = __builtin_bit_cast(half8, u);
    }
}

static __device__ const f32x16 kZero16 = {0,0,0,0, 0,0,0,0, 0,0,0,0, 0,0,0,0};

// ============================================================
// Main r25: r24 geometry (32-row waves, 4-wave blocks, 2 blk/CU,
// 2 waves/SIMD) but W delivery SPLIT ACROSS BOTH PIPES.
// Post-mortem r24 (185us = 4440cy/CU-layer): LDS delivery-bound —
// 224 ds_read_b128 x ~12cy = 2690cy/CU-layer (all 8 waves re-read the
// SAME 28KB of W via LDS) while the vector-memory path sat idle.
// r19 calibration: wave-wide dwordx4 from L1/L2-resident stream ~
// 11-12 cy — SAME per-KB rate as ds_read_b128. So:
//  - ks 0..2 (12 frags) staged via global_load_lds + ds_read (LDS pipe)
//  - ks 3..6 (16 frags) read DIRECT global->reg (TCP pipe; 16KB
//    working set is L1-cached across the CU's 8 waves)
// Issue order/layer: ds_reads first (needed at ks0) -> TCP burst
// (first consumed at ks3, ~400cy after issue -> L2 latency covered;
// no cross-layer holding, no anchors, sink-safe by construction) ->
// staging W(l+1) (drained by end-of-layer barrier, full layer slack).
// Delivery/CU-layer: LDS ~1350cy + TCP ~1540cy in parallel -> ~1550
// vs r24's 2690. L2 traffic unchanged (28KB/CU-layer). VGPR: acc 64
// + bh 28 + wbg 64 + wbl temps ~ 210 <= 256 (2 waves/SIMD cap).
// h handoff in regs (permlane); W bytes identical -> absmax 0.09375.
// ============================================================
__global__ __launch_bounds__(256, 2)
void actor_main(const float* __restrict__ x,
                const _Float16* __restrict__ wsh,
                const _Float16* __restrict__ w0sh,
                const float* __restrict__ bpad,
                const float* __restrict__ woutp,
                const float* __restrict__ bout,
                float* __restrict__ out) {
    __shared__ __align__(16) _Float16 wlds[2 * FRAGSL * 512];  // 2 x 12KB
    const int tid  = threadIdx.x;
    const int lane = tid & 63;
    const int wid  = tid >> 6;                   // 0..3
    const int g = lane >> 5, b31 = lane & 31;
    const int rowbase = blockIdx.x * BROWS + wid * ROWS;   // my wave's 32 rows

    f32x16 acc[NTT];                 //  64 VGPR: 4 independent MFMA chains
    half8 bh[KS];                    //  28 VGPR: B-frags (next-layer input)
    half8 wbl[KSL][NTT];             //  48 VGPR: LDS-sourced W (ks 0..2)
    half8 wbg[KST][NTT];             //  64 VGPR: TCP-sourced W (ks 3..6)

    // ---- stage W(0) LDS portion -> buf0 (async; overlaps input layer) ----
#pragma unroll
    for (int f = 0; f < FPW; ++f) {
        const int fr = wid * FPW + f;
        stage16(wsh + fr * 512 + lane * 8, wlds + fr * 512);
    }

    // ---- input layer (K=64 = 4 k-steps of 16), x hi/lo f16 split ----
    {
        half8 w0[4][NTT];
#pragma unroll
        for (int ks = 0; ks < 4; ++ks)
#pragma unroll
            for (int nt = 0; nt < NTT; ++nt)
                w0[ks][nt] = *(const half8*)(w0sh + (ks * NTT + nt) * 512 + lane * 8);
#pragma unroll
        for (int nt = 0; nt < NTT; ++nt)
#pragma unroll
            for (int qd = 0; qd < 4; ++qd) {
                f32x4 tq = *(const f32x4*)(bpad + nt * 32 + 8 * qd + 4 * g);
#pragma unroll
                for (int r = 0; r < 4; ++r) acc[nt][4 * qd + r] = tq[r];
            }
        const float* xr = x + (rowbase + b31) * DIN;
#pragma unroll
        for (int ks = 0; ks < 4; ++ks) {
            half8 xhi, xlo;
            split8(xr + ks * 16 + g * 8, xhi, xlo);
#pragma unroll
            for (int nt = 0; nt < NTT; ++nt) {
                acc[nt] = __builtin_amdgcn_mfma_f32_32x32x16_f16(w0[ks][nt], xhi, acc[nt], 0, 0, 0);
                acc[nt] = __builtin_amdgcn_mfma_f32_32x32x16_f16(w0[ks][nt], xlo, acc[nt], 0, 0, 0);
            }
        }
    }
    pack_bh(acc, bh);                // h0 in regs
    __syncthreads();                 // drains W(0) staging (vmcnt(0) + barrier)

    // -------- 100 hidden layers: dual-pipe W delivery, 1 barrier/layer -----
#pragma unroll 1
    for (int l = 0; l < NLAYERS; ++l) {
        const _Float16* rb = wlds + (l & 1) * (FRAGSL * 512);      // W(l) ks0..2
        _Float16* sb = (_Float16*)wlds + ((l + 1) & 1) * (FRAGSL * 512);
        const _Float16* wg = wsh + l * WSH_LAYER_HALVES;           // W(l) global
        const int ln = (l + 1 < NLAYERS) ? l + 1 : NLAYERS - 1;
        const _Float16* wn = wsh + ln * WSH_LAYER_HALVES;

        // (1) LDS pipe: ks 0..2 -> regs (needed first, at ks0)
#pragma unroll
        for (int ks = 0; ks < KSL; ++ks)
#pragma unroll
            for (int nt = 0; nt < NTT; ++nt)
                wbl[ks][nt] = *(const half8*)(rb + (ks * NTT + nt) * 512 + lane * 8);
        // (2) TCP pipe: ks 3..6 -> regs (first consumed at ks3; L1-shared
        //     across the CU's 8 waves; counted vmcnt at use)
#pragma unroll
        for (int ks = 0; ks < KST; ++ks)
#pragma unroll
            for (int nt = 0; nt < NTT; ++nt)
                wbg[ks][nt] = *(const half8*)(wg + ((KSL + ks) * NTT + nt) * 512 + lane * 8);
        // (3) stage W(l+1) ks0..2 into the other buffer (drained at barrier)
#pragma unroll
        for (int f = 0; f < FPW; ++f) {
            const int fr = wid * FPW + f;
            stage16(wn + fr * 512 + lane * 8, sb + fr * 512);
        }
        // (4) 28 MFMAs, 4 independent chains; ks0..2 from wbl, ks3..6 wbg
#pragma unroll
        for (int ks = 0; ks < KS; ++ks) {
#pragma unroll
            for (int nt = 0; nt < NTT; ++nt) {
                const half8 wfrag = (ks < KSL) ? wbl[ks][nt] : wbg[ks - KSL][nt];
                acc[nt] = __builtin_amdgcn_mfma_f32_32x32x16_f16(
                    wfrag, bh[ks], (ks == 0 ? kZero16 : acc[nt]), 0, 0, 0);
            }
        }
        if (l < NLAYERS - 1)
            pack_bh(acc, bh);        // next layer's input (regs only)
        __syncthreads();             // staging drained + buffers flip
    }
    // acc[nt] = pre-activation of layer 99 (f32) for all 128 neurons

    // ---------------- head: leaky + dot(W_out), wave-local ----------------
    float s = 0.f;
#pragma unroll
    for (int nt = 0; nt < NTT; ++nt)
#pragma unroll
        for (int qd = 0; qd < 4; ++qd) {
            f32x4 w4 = *(const f32x4*)(woutp + nt * 32 + 8 * qd + 4 * g);
#pragma unroll
            for (int r = 0; r < 4; ++r) {
                float a = acc[nt][4 * qd + r];
                float v = fmaxf(a, 0.01f * a);
                s += v * w4[r];
            }
        }
    s += __shfl_xor(s, 32);          // combine the two k-groups (same batch row)
    if (lane < 32) {
        float tot = s + bout[0];
        out[rowbase + b31] = tanhf(tot) * 4.5f + 5.5f;   // (tanh+1)/2*9 + 1
    }
}

extern "C" void kernel_launch(void* const* d_in, const int* in_sizes, int n_in,
                              void* d_out, int out_size, void* d_ws, size_t ws_size,
                              hipStream_t stream) {
    const float* x    = (const float*)d_in[0];
    const float* Win  = (const float*)d_in[1];
    const float* bin  = (const float*)d_in[2];
    const float* Ws   = (const float*)d_in[3];
    const float* bs   = (const float*)d_in[4];
    const float* Wout = (const float*)d_in[5];
    const float* bout = (const float*)d_in[6];
    float* out = (float*)d_out;

    char* ws = (char*)d_ws;
    _Float16* wsh  = (_Float16*)ws;
    _Float16* w0sh = wsh + WSH_HALVES;
    float* bpad  = (float*)(ws + OFF_BPAD_B);
    float* woutp = (float*)(ws + OFF_WOUT_B);

    hipLaunchKernelGGL(actor_prep, dim3(NLAYERS * KS + 4 + 1), dim3(256), 0, stream,
                       Win, bin, Ws, bs, Wout, wsh, w0sh, bpad, woutp);

    const int nrows = in_sizes[0] / DIN;   // 65536
    hipLaunchKernelGGL(actor_main, dim3(nrows / BROWS), dim3(WAVES * 64), 0, stream,
                       x, wsh, w0sh, bpad, woutp, bout, out);
}

// Round 9
// 262.373 us; speedup vs baseline: 1.1462x; 1.1462x over previous
//
#include <hip/hip_runtime.h>
#include <cmath>

// ---------------- problem constants ----------------
#define NLAYERS 100      // hidden layers (scan)
#define DIN     64       // input features
#define WDIM    100      // hidden width
#define NTT     4        // 4 n-tiles of 32 (128 neuron cols; bias col = 100)
#define ROWS    32       // rows per WAVE
#define WAVES   4        // waves per block
#define BROWS   (WAVES * ROWS)   // 128 rows per block
#define KS      7        // 7 k-steps of 16 -> K=112 (useful 101)
#define KSL     4        // ks 0..3 delivered via LDS (staged, double-buffered)
#define KST     (KS - KSL)       // ks 4..6 delivered via pinned-asm TCP loads
#define FRAGSL  (KSL * NTT)      // 16 staged frags per layer
#define FPW     (FRAGSL / WAVES) // 4 frags staged per wave

typedef _Float16 half8  __attribute__((ext_vector_type(8)));
typedef _Float16 half2v __attribute__((ext_vector_type(2)));
typedef __fp16   fp16x2 __attribute__((ext_vector_type(2)));
typedef float    f32x4  __attribute__((ext_vector_type(4)));
typedef float    f32x16 __attribute__((ext_vector_type(16)));
typedef unsigned uint4v __attribute__((ext_vector_type(4)));

// ---------------- workspace layout ----------------
// wsh: [l][ks7][nt4][lane][8] — frag stride 512 halves (1024 B).
// A-frag (32x32x16, operand-swapped W^T): lane -> neuron n = nt*32+(lane&31);
// elem j -> k = ks*16 + (lane>>5)*8 + j.
//   k<100 && n<100   -> Ws[l][k][n]
//   k==100 && n<100  -> bs[l][n]      (bias row vs h col 100 == 1.0)
//   k==100 && n==100 -> 1.0           (bias col self-sustains)
#define WSH_LAYER_HALVES (KS * NTT * 64 * 8)             // 14336 (28672 B)
#define WSH_HALVES       (NLAYERS * WSH_LAYER_HALVES)    // 1,433,600
#define W0_HALVES        (4 * NTT * 64 * 8)              // 8192 (input, K=64 = 4 ks)
#define BPAD_FLOATS      128                             // b_in padded; col 100 = 1.0
#define OFF_BPAD_B       ((WSH_HALVES + W0_HALVES) * 2)
#define OFF_WOUT_B       (OFF_BPAD_B + BPAD_FLOATS * 4)
#define WOUT_FLOATS      128

// ============================================================
// prep v2 (unchanged): one block per (l,ks); coalesced row reads ->
// 8KB LDS f32 tile [16k][128n] -> coalesced half8 frag stores.
// ============================================================
__global__ __launch_bounds__(256)
void actor_prep(const float* __restrict__ Win, const float* __restrict__ bin,
                const float* __restrict__ Ws,  const float* __restrict__ bs,
                const float* __restrict__ Wout,
                _Float16* __restrict__ wsh, _Float16* __restrict__ w0sh,
                float* __restrict__ bpad, float* __restrict__ woutp) {
    __shared__ float tile[16 * 128];
    const int bid = blockIdx.x, tid = threadIdx.x;
    if (bid < NLAYERS * KS) {                       // hidden-layer weights
        const int l = bid / KS, ks = bid % KS;
#pragma unroll
        for (int e = 0; e < 8; ++e) {
            int idx = tid + 256 * e;                // coalesced: tid fastest
            int kk = idx >> 7, nn = idx & 127;
            int k = ks * 16 + kk;
            float v = 0.f;
            if (k < WDIM && nn < WDIM)        v = Ws[(l * WDIM + k) * WDIM + nn];
            else if (k == WDIM && nn < WDIM)  v = bs[l * WDIM + nn];   // bias row
            else if (k == WDIM && nn == WDIM) v = 1.0f;                // bias col alive
            tile[idx] = v;
        }
        __syncthreads();
        const int lane = tid & 63, nt = tid >> 6;
        const int g = lane >> 5, n = nt * 32 + (lane & 31);
        half8 o;
#pragma unroll
        for (int j = 0; j < 8; ++j) o[j] = (_Float16)tile[(g * 8 + j) * 128 + n];
        *(half8*)(wsh + (((l * KS + ks) * NTT + nt) << 9) + lane * 8) = o;
        return;
    }
    int b2 = bid - NLAYERS * KS;
    if (b2 < 4) {                                   // input layer (K=64)
        const int ks = b2;
#pragma unroll
        for (int e = 0; e < 8; ++e) {
            int idx = tid + 256 * e;
            int kk = idx >> 7, nn = idx & 127;
            int k = ks * 16 + kk;                   // < 64
            tile[idx] = (nn < WDIM) ? Win[k * WDIM + nn] : 0.f;
        }
        __syncthreads();
        const int lane = tid & 63, nt = tid >> 6;
        const int g = lane >> 5, n = nt * 32 + (lane & 31);
        half8 o;
#pragma unroll
        for (int j = 0; j < 8; ++j) o[j] = (_Float16)tile[(g * 8 + j) * 128 + n];
        *(half8*)(w0sh + ((ks * NTT + nt) << 9) + lane * 8) = o;
        return;
    }
    // last block: padded b_in (col 100 = 1.0 seed) + padded W_out
    if (tid < BPAD_FLOATS) {
        bpad[tid] = (tid < WDIM) ? bin[tid] : (tid == WDIM ? 1.0f : 0.f);
    } else {
        int t = tid - BPAD_FLOATS;
        if (t < WOUT_FLOATS) woutp[t] = (t < WDIM) ? Wout[t] : 0.f;
    }
}

// async global->LDS, 16 B per lane, zero VGPR cost.
// g: per-lane source (base + lane*16B); l: WAVE-UNIFORM LDS frag base
// (HW adds lane*16). [m97: emits global_load_lds_dwordx4]
__device__ __forceinline__ void stage16(const _Float16* __restrict__ g,
                                        _Float16* l) {
    __builtin_amdgcn_global_load_lds(
        (const __attribute__((address_space(1))) unsigned*)g,
        (__attribute__((address_space(3))) unsigned*)l, 16, 0, 0);
}

// split fp32 -> hi/lo fp16 (layer-0 input only: keep input fidelity)
__device__ __forceinline__ void split8(const float* __restrict__ p, half8& hi, half8& lo) {
    f32x4 u0 = *(const f32x4*)p;
    f32x4 u1 = *(const f32x4*)(p + 4);
    float v[8] = {u0[0], u0[1], u0[2], u0[3], u1[0], u1[1], u1[2], u1[3]};
#pragma unroll
    for (int e = 0; e < 8; e += 2) {
        fp16x2 h = __builtin_amdgcn_cvt_pkrtz(v[e], v[e + 1]);
        float r0 = v[e]     - (float)h[0];
        float r1 = v[e + 1] - (float)h[1];
        fp16x2 l = __builtin_amdgcn_cvt_pkrtz(r0, r1);
        hi[e] = (_Float16)h[0]; hi[e + 1] = (_Float16)h[1];
        lo[e] = (_Float16)l[0]; lo[e + 1] = (_Float16)l[1];
    }
}

// RNE f16 cast pair + packed-f16 leaky -> one dword (same ops/precision
// as the original LDS epilogue: scalar RNE cast, then max(p, 0.01p) in f16)
__device__ __forceinline__ unsigned pack2(float a, float b) {
    half2v p; p[0] = (_Float16)a; p[1] = (_Float16)b;
    const half2v slope = {(_Float16)0.01f, (_Float16)0.01f};
    p = __builtin_elementwise_max(p, p * slope);
    return __builtin_bit_cast(unsigned, p);
}

// acc -> bh: leaky+f16 pack + lane-half exchange (v_permlane32_swap).
// C/D layout (m74/m101): col=b31, row=(reg&3)+8*(reg>>2)+4g. B-frag:
// lane b31 holds k=ks*16+g*8+j; j0..3 from lane b31 regs r0=8*(ks&1)+0..3,
// j4..7 from lane b31+32 same regs -> one permlane swap per dword pair.
// Bit-identical to the LDS h path (absmax constant 0.09375 since r17).
__device__ __forceinline__ void pack_bh(const f32x16 (&acc)[NTT], half8 (&bh)[KS]) {
#pragma unroll
    for (int ks = 0; ks < KS; ++ks) {
        const int r0 = 8 * (ks & 1);
        const f32x16 a = acc[ks >> 1];
        unsigned lo0 = pack2(a[r0 + 0], a[r0 + 1]);
        unsigned lo1 = pack2(a[r0 + 2], a[r0 + 3]);
        unsigned hi0 = pack2(a[r0 + 4], a[r0 + 5]);
        unsigned hi1 = pack2(a[r0 + 6], a[r0 + 7]);
        asm volatile("v_permlane32_swap_b32 %0, %1" : "+v"(lo0), "+v"(hi0));
        asm volatile("v_permlane32_swap_b32 %0, %1" : "+v"(lo1), "+v"(hi1));
        uint4v u = {lo0, lo1, hi0, hi1};
        bh[ks] = __builtin_bit_cast(half8, u);
    }
}

static __device__ const f32x16 kZero16 = {0,0,0,0, 0,0,0,0, 0,0,0,0, 0,0,0,0};

// ============================================================
// Main r26: r24 geometry (32-row waves, 4-wave blocks, 2 blk/CU,
// 2 waves/SIMD) + dual-pipe W delivery with PINNED asm TCP loads.
// Post-mortem r25 (243us, VGPR=64): plain C global->reg loads with a
// distant consumer get SUNK to just-before-use by hipcc (3rd time:
// r19/r20/r25) — the dual-pipe overlap never existed; each ks group
// stalled ~200cy on L1/L2. r24 (185us = 4440cy/CU-layer) is LDS-pipe
// bound: 224 ds_read_b128 + 56 stage-writes ~ 3250cy busy, TCP idle.
// Fix: ks0..3 (16 frags) via LDS staging (as r24); ks4..6 (12 frags)
// via 12 asm VOLATILE global_load_dwordx4 pinned at the TOP of the
// layer body — volatile asm cannot be sunk. Async-correctness (rule
// #18): compiler treats asm loads as complete at the asm, so ONE
// "s_waitcnt vmcnt(0)" asm sits between ks3 and ks4 MFMAs with all 12
// dest regs threaded "+v" (data-deps order every consumer after it)
// + "memory" clobber (staging can't drift below). vmcnt(0) also
// covers the 4 stage16 (same ~600cy slack) -> end-of-layer barrier
// drain is free. Delivery/CU-layer: LDS 128 reads + 32 writes ~1800cy
// || TCP 96 loads ~1500cy (12KB L1-resident, shared by 8 waves).
// h handoff in regs (permlane); W bytes identical -> absmax 0.09375.
// ============================================================
__global__ __launch_bounds__(256, 2)
void actor_main(const float* __restrict__ x,
                const _Float16* __restrict__ wsh,
                const _Float16* __restrict__ w0sh,
                const float* __restrict__ bpad,
                const float* __restrict__ woutp,
                const float* __restrict__ bout,
                float* __restrict__ out) {
    __shared__ __align__(16) _Float16 wlds[2 * FRAGSL * 512];  // 2 x 16KB
    const int tid  = threadIdx.x;
    const int lane = tid & 63;
    const int wid  = tid >> 6;                   // 0..3
    const int g = lane >> 5, b31 = lane & 31;
    const int rowbase = blockIdx.x * BROWS + wid * ROWS;   // my wave's 32 rows

    f32x16 acc[NTT];                 //  64 VGPR: 4 independent MFMA chains
    half8 bh[KS];                    //  28 VGPR: B-frags (next-layer input)

    // ---- stage W(0) LDS portion -> buf0 (async; overlaps input layer) ----
#pragma unroll
    for (int f = 0; f < FPW; ++f) {
        const int fr = wid * FPW + f;
        stage16(wsh + fr * 512 + lane * 8, wlds + fr * 512);
    }

    // ---- input layer (K=64 = 4 k-steps of 16), x hi/lo f16 split ----
    {
        half8 w0[4][NTT];
#pragma unroll
        for (int ks = 0; ks < 4; ++ks)
#pragma unroll
            for (int nt = 0; nt < NTT; ++nt)
                w0[ks][nt] = *(const half8*)(w0sh + (ks * NTT + nt) * 512 + lane * 8);
#pragma unroll
        for (int nt = 0; nt < NTT; ++nt)
#pragma unroll
            for (int qd = 0; qd < 4; ++qd) {
                f32x4 tq = *(const f32x4*)(bpad + nt * 32 + 8 * qd + 4 * g);
#pragma unroll
                for (int r = 0; r < 4; ++r) acc[nt][4 * qd + r] = tq[r];
            }
        const float* xr = x + (rowbase + b31) * DIN;
#pragma unroll
        for (int ks = 0; ks < 4; ++ks) {
            half8 xhi, xlo;
            split8(xr + ks * 16 + g * 8, xhi, xlo);
#pragma unroll
            for (int nt = 0; nt < NTT; ++nt) {
                acc[nt] = __builtin_amdgcn_mfma_f32_32x32x16_f16(w0[ks][nt], xhi, acc[nt], 0, 0, 0);
                acc[nt] = __builtin_amdgcn_mfma_f32_32x32x16_f16(w0[ks][nt], xlo, acc[nt], 0, 0, 0);
            }
        }
    }
    pack_bh(acc, bh);                // h0 in regs
    __syncthreads();                 // drains W(0) staging (vmcnt(0) + barrier)

    // -------- 100 hidden layers: dual-pipe W delivery, 1 barrier/layer -----
#pragma unroll 1
    for (int l = 0; l < NLAYERS; ++l) {
        const _Float16* rb = wlds + (l & 1) * (FRAGSL * 512);      // W(l) ks0..3
        _Float16* sb = (_Float16*)wlds + ((l + 1) & 1) * (FRAGSL * 512);
        const _Float16* wg = wsh + l * WSH_LAYER_HALVES;           // W(l) global
        const int ln = (l + 1 < NLAYERS) ? l + 1 : NLAYERS - 1;
        const _Float16* wn = wsh + ln * WSH_LAYER_HALVES;

        // (1) stage W(l+1) ks0..3 into the other buffer (zero-VGPR; drained
        //     by the mid-layer vmcnt(0) -> end barrier is free)
#pragma unroll
        for (int f = 0; f < FPW; ++f) {
            const int fr = wid * FPW + f;
            stage16(wn + fr * 512 + lane * 8, sb + fr * 512);
        }
        // (2) TCP pipe: ks4..6 -> regs via PINNED volatile asm loads
        //     (cannot be sunk; ~600cy of ks0..3 MFMA cover before use)
        uint4v wbg[KST][NTT];
#pragma unroll
        for (int ks = 0; ks < KST; ++ks) {
            const _Float16* bp = wg + (KSL + ks) * NTT * 512 + lane * 8;
            asm volatile("global_load_dwordx4 %0, %1, off"
                         : "=v"(wbg[ks][0]) : "v"(bp));
            asm volatile("global_load_dwordx4 %0, %1, off offset:1024"
                         : "=v"(wbg[ks][1]) : "v"(bp));
            asm volatile("global_load_dwordx4 %0, %1, off offset:2048"
                         : "=v"(wbg[ks][2]) : "v"(bp));
            asm volatile("global_load_dwordx4 %0, %1, off offset:3072"
                         : "=v"(wbg[ks][3]) : "v"(bp));
        }
        // (3) LDS pipe: ks0..3 MFMAs, W frags ds_read JIT (cheap, 2w/SIMD)
#pragma unroll
        for (int ks = 0; ks < KSL; ++ks)
#pragma unroll
            for (int nt = 0; nt < NTT; ++nt) {
                half8 wfrag = *(const half8*)(rb + (ks * NTT + nt) * 512 + lane * 8);
                acc[nt] = __builtin_amdgcn_mfma_f32_32x32x16_f16(
                    wfrag, bh[ks], (ks == 0 ? kZero16 : acc[nt]), 0, 0, 0);
            }
        // (4) wait: all TCP loads (and staging) complete; dest regs threaded
        //     through so no consumer can be hoisted above (rule #18)
        asm volatile("s_waitcnt vmcnt(0)"
                     : "+v"(wbg[0][0]), "+v"(wbg[0][1]), "+v"(wbg[0][2]), "+v"(wbg[0][3]),
                       "+v"(wbg[1][0]), "+v"(wbg[1][1]), "+v"(wbg[1][2]), "+v"(wbg[1][3]),
                       "+v"(wbg[2][0]), "+v"(wbg[2][1]), "+v"(wbg[2][2]), "+v"(wbg[2][3])
                     :: "memory");
        // (5) ks4..6 MFMAs from TCP-loaded regs
#pragma unroll
        for (int ks = KSL; ks < KS; ++ks)
#pragma unroll
            for (int nt = 0; nt < NTT; ++nt)
                acc[nt] = __builtin_amdgcn_mfma_f32_32x32x16_f16(
                    __builtin_bit_cast(half8, wbg[ks - KSL][nt]), bh[ks], acc[nt], 0, 0, 0);
        if (l < NLAYERS - 1)
            pack_bh(acc, bh);        // next layer's input (regs only)
        __syncthreads();             // buffers flip (staging already drained)
    }
    // acc[nt] = pre-activation of layer 99 (f32) for all 128 neurons

    // ---------------- head: leaky + dot(W_out), wave-local ----------------
    float s = 0.f;
#pragma unroll
    for (int nt = 0; nt < NTT; ++nt)
#pragma unroll
        for (int qd = 0; qd < 4; ++qd) {
            f32x4 w4 = *(const f32x4*)(woutp + nt * 32 + 8 * qd + 4 * g);
#pragma unroll
            for (int r = 0; r < 4; ++r) {
                float a = acc[nt][4 * qd + r];
                float v = fmaxf(a, 0.01f * a);
                s += v * w4[r];
            }
        }
    s += __shfl_xor(s, 32);          // combine the two k-groups (same batch row)
    if (lane < 32) {
        float tot = s + bout[0];
        out[rowbase + b31] = tanhf(tot) * 4.5f + 5.5f;   // (tanh+1)/2*9 + 1
    }
}

extern "C" void kernel_launch(void* const* d_in, const int* in_sizes, int n_in,
                              void* d_out, int out_size, void* d_ws, size_t ws_size,
                              hipStream_t stream) {
    const float* x    = (const float*)d_in[0];
    const float* Win  = (const float*)d_in[1];
    const float* bin  = (const float*)d_in[2];
    const float* Ws   = (const float*)d_in[3];
    const float* bs   = (const float*)d_in[4];
    const float* Wout = (const float*)d_in[5];
    const float* bout = (const float*)d_in[6];
    float* out = (float*)d_out;

    char* ws = (char*)d_ws;
    _Float16* wsh  = (_Float16*)ws;
    _Float16* w0sh = wsh + WSH_HALVES;
    float* bpad  = (float*)(ws + OFF_BPAD_B);
    float* woutp = (float*)(ws + OFF_WOUT_B);

    hipLaunchKernelGGL(actor_prep, dim3(NLAYERS * KS + 4 + 1), dim3(256), 0, stream,
                       Win, bin, Ws, bs, Wout, wsh, w0sh, bpad, woutp);

    const int nrows = in_sizes[0] / DIN;   // 65536
    hipLaunchKernelGGL(actor_main, dim3(nrows / BROWS), dim3(WAVES * 64), 0, stream,
                       x, wsh, w0sh, bpad, woutp, bout, out);
}